// Round 14
// baseline (271.201 us; speedup 1.0000x reference)
//
#include <hip/hip_runtime.h>
#include <stdint.h>

// FixedConv1DPriorEnsemble: DZ=30 ensemble of conv nets over embedded tokens.
// V=32000 E=8 DZ=30 C=10, CH=(4,8,8), K=3, S=(2,2,1), B=512, L=4096.
//
// History: R8 387 (precompute x); R11 318.7 (f16 dot2); R13 256.3 (stages 2+3
//   on mfma_f32_16x16x32_f16 via shift-packing; ens 172us; absmax stable
//   1.56e-2 -> MFMA A/B/C mappings verified). VALUBusy still 93%: stage-1's
//   256 dot2/thread dominates.
// R14: stage 1 on MFMA too. K = 8e x 4q = 32 exact; B col n = output position
//   16t+n holding x[e][2p..2p+3] (q=3 tap zero-weighted); A rows 0-3 = out
//   channels (rows 4-15 zero -> quad-0 lanes store). 17 MFMAs/wave replace
//   256 dot2. Loads clamped in-bounds at edges, stores masked (tail deleted).
//   Also: wpack fused into the prep/embed kernel (one fewer launch).

typedef _Float16 f16;
typedef f16 f16x2 __attribute__((ext_vector_type(2)));
typedef f16 f16x8 __attribute__((ext_vector_type(8)));
typedef float f32x4 __attribute__((ext_vector_type(4)));

static __device__ __forceinline__ uint32_t bch(f16x2 h) {
  union { uint32_t u; f16x2 h; } v; v.h = h; return v.u;
}

// ---- prep: embed x_f16 + pack MFMA A-fragments (one kernel) ----
// a1[d][lane][8]: m=lane&15,quad=lane>>4; k=quad*8+j -> e=quad*2+(j>>2),q=j&3
//   val = (m<4 && q<3) ? W1[m][e][q] : 0
// a2[d][lane][8]: c1=quad, j tap-index:
//   m<8: j<3 ? W2[m][c1][j] : 0 ; m>=8: 2<=j<5 ? W2[m-8][c1][j-2] : 0
// a3[d][lane][8]: k -> c2=quad*2+(j>>2), t=j&3:
//   m<8: t<3 ? W3[m][c2][t] : 0 ; m>=8: t>=1 ? W3[m-8][c2][t-1] : 0
__global__ __launch_bounds__(256) void prep_kernel(
    const int* __restrict__ ids, const float* __restrict__ mask,
    const float* __restrict__ tbl,
    const float* __restrict__ W1, const float* __restrict__ W2,
    const float* __restrict__ W3,
    f16* __restrict__ x, f16* __restrict__ a1,
    f16* __restrict__ a2, f16* __restrict__ a3) {
  const int blk = blockIdx.x;
  if (blk < 4096) {                            // embed: 2 tokens/thread
    const int b  = blk >> 3;
    const int l0 = ((blk & 7) * 256 + threadIdx.x) * 2;
    const int2   iv = *(const int2*)(ids + (size_t)b * 4096 + l0);
    const float2 mv = *(const float2*)(mask + (size_t)b * 4096 + l0);
    const float4* t4 = (const float4*)tbl;
    const float4 a0 = t4[(size_t)iv.x * 2], A1 = t4[(size_t)iv.x * 2 + 1];
    const float4 c0 = t4[(size_t)iv.y * 2], C1 = t4[(size_t)iv.y * 2 + 1];
    const float r0[8] = {a0.x, a0.y, a0.z, a0.w, A1.x, A1.y, A1.z, A1.w};
    const float r1[8] = {c0.x, c0.y, c0.z, c0.w, C1.x, C1.y, C1.z, C1.w};
    f16* xb = x + (size_t)b * 8 * 4096 + l0;
    #pragma unroll
    for (int e = 0; e < 8; ++e) {
      f16x2 p; p.x = (f16)(r0[e] * mv.x); p.y = (f16)(r1[e] * mv.y);
      *(f16x2*)(xb + e * 4096) = p;
    }
  } else {                                     // A-fragment packing
    const int i = (blk - 4096) * 256 + threadIdx.x;
    if (i < 1920) {                            // a1: 30*64
      const int d = i >> 6, lane = i & 63, quad = lane >> 4, m = lane & 15;
      f16x8 v;
      #pragma unroll
      for (int j = 0; j < 8; ++j) {
        const int e = quad * 2 + (j >> 2), q = j & 3;
        float val = 0.0f;
        if (m < 4 && q < 3) val = W1[d * 96 + m * 24 + e * 3 + q];
        v[j] = (f16)val;
      }
      *(f16x8*)(a1 + ((size_t)d * 64 + lane) * 8) = v;
    } else if (i < 3840) {                     // a2: 30*64
      const int idx = i - 1920, d = idx >> 6, lane = idx & 63;
      const int quad = lane >> 4, m = lane & 15;
      f16x8 v;
      #pragma unroll
      for (int j = 0; j < 8; ++j) {
        float val = 0.0f;
        if (m < 8)  { if (j < 3)           val = W2[d * 96 + m * 12 + quad * 3 + j]; }
        else        { if (j >= 2 && j < 5) val = W2[d * 96 + (m - 8) * 12 + quad * 3 + (j - 2)]; }
        v[j] = (f16)val;
      }
      *(f16x8*)(a2 + ((size_t)d * 64 + lane) * 8) = v;
    } else if (i < 5760) {                     // a3: 30*64
      const int idx = i - 3840, d = idx >> 6, lane = idx & 63;
      const int quad = lane >> 4, m = lane & 15;
      f16x8 v;
      #pragma unroll
      for (int j = 0; j < 8; ++j) {
        const int c2 = quad * 2 + (j >> 2), t = j & 3;
        float val = 0.0f;
        if (m < 8)  { if (t < 3)  val = W3[d * 192 + m * 24 + c2 * 3 + t]; }
        else        { if (t >= 1) val = W3[d * 192 + (m - 8) * 24 + c2 * 3 + (t - 1)]; }
        v[j] = (f16)val;
      }
      *(f16x8*)(a3 + ((size_t)d * 64 + lane) * 8) = v;
    }
  }
}

// ---------------- fast path: all three conv stages on MFMA ----------------
__global__ __launch_bounds__(256, 8) void ensemble_f16_kernel(
    const f16* __restrict__ x,        // [512][8][4096]
    const f16* __restrict__ a1,       // stage-1 A-fragments [30][64][8]
    const f16* __restrict__ a2,       // stage-2 A-fragments [30][64][8]
    const f16* __restrict__ a3,       // stage-3 A-fragments [30][64][8]
    const float* __restrict__ z,
    const float* __restrict__ b1, const float* __restrict__ b2,
    const float* __restrict__ b3,
    const float* __restrict__ Wh, const float* __restrict__ bh,
    float* __restrict__ part)         // [30][2][512][10]
{
  const int tid  = threadIdx.x;
  const int b    = blockIdx.x / 60;   // same-b blocks consecutive (x L2 reuse)
  const int rem  = blockIdx.x - b * 60;
  const int d    = rem >> 1;
  const int half = rem & 1;

  // h1 f16[4][1096] (8768B); h2 f16[8][516] overlay; pool f32[8][128] overlay
  __shared__ float smem[2192];
  __shared__ float pooled[8];
  f16* h1f = (f16*)smem;
  f16* h2f = (f16*)smem;

  const int l_lo = half ? 1024 : 0;
  const int l_hi = half ? 2047 : 1029;
  const int j_lo = half ? 512  : 0;
  const int j_hi = half ? 1023 : 514;
  const int o_lo = half ? 512  : 0;
  const int o_hi = half ? 1021 : 512;
  const int span  = l_hi - l_lo;             // 1029 / 1023
  const int jspan = j_hi - j_lo;             // 514 / 511
  const int ospan = o_hi - o_lo;             // 512 / 509
  const int nt1   = (span + 15) >> 4;        // 65 / 64
  const int nt2   = (jspan + 31) >> 5;       // 17 / 16

  const f16* xb = x + (size_t)b * 8 * 4096;

  const int w    = tid >> 6;
  const int lane = tid & 63;
  const int quad = lane >> 4;
  const int n    = lane & 15;

  // zero h1 tail region [1020,1096) x 4 rows (stage-2 tiles over-read; stage-1
  // masked stores rewrite the valid overlap [1020,span) after the barrier).
  for (int idx = tid; idx < 304; idx += 256)
    h1f[(idx & 3) * 1096 + 1020 + (idx >> 2)] = (f16)0.0f;
  __syncthreads();

  // ---- stage 1 (MFMA): rows 0-3 = out channels, cols = 16 output positions ----
  {
    const f16x8 af1 = *(const f16x8*)(a1 + ((size_t)d * 64 + lane) * 8);
    f32x4 cinit1 = {0.0f, 0.0f, 0.0f, 0.0f};
    if (quad == 0) cinit1 = *(const f32x4*)(b1 + d * 4);
    for (int i = 0; i < 17; ++i) {
      const int t = w + 4 * i;                // wave-uniform
      if (t < nt1) {
        const int rel = 16 * t + n;
        const int lp  = l_lo + ((rel < span) ? rel : 0);   // clamp: in-bounds
        const f16* xe0 = xb + (2 * quad) * 4096 + 2 * lp;  // e = 2*quad
        union { f16x8 v; f16x2 q[4]; } u;
        u.q[0] = *(const f16x2*)xe0;               // q=0,1
        u.q[1] = *(const f16x2*)(xe0 + 2);         // q=2,3
        u.q[2] = *(const f16x2*)(xe0 + 4096);      // e+1, q=0,1
        u.q[3] = *(const f16x2*)(xe0 + 4098);      // e+1, q=2,3
        const f32x4 C = __builtin_amdgcn_mfma_f32_16x16x32_f16(af1, u.v, cinit1, 0, 0, 0);
        if (quad == 0 && rel < span) {
          #pragma unroll
          for (int r = 0; r < 4; ++r)
            h1f[r * 1096 + rel] = (f16)fmaxf(C[r], 0.0f);
        }
      }
    }
  }
  __syncthreads();

  // ---- stage 2 (MFMA): rows 0-7 = c2 @ j, rows 8-15 = c2 @ j+1 ----
  f32x4 Ci[5];
  {
    const f16x8 af2 = *(const f16x8*)(a2 + ((size_t)d * 64 + lane) * 8);
    const f32x4 cinit2 = *(const f32x4*)(b2 + d * 8 + (quad & 1) * 4);
    #pragma unroll
    for (int i = 0; i < 5; ++i) {
      const int t = w + 4 * i;
      if (t < nt2) {
        const f16* bp = h1f + quad * 1096 + 64 * t + 4 * n;
        union { f16x8 v; f16x2 q[4]; } u;
        u.q[0] = *(const f16x2*)bp;
        u.q[1] = *(const f16x2*)(bp + 2);
        u.q[2] = *(const f16x2*)(bp + 4);
        u.q[3] = *(const f16x2*)(bp + 6);
        Ci[i] = __builtin_amdgcn_mfma_f32_16x16x32_f16(af2, u.v, cinit2, 0, 0, 0);
      } else {
        Ci[i] = cinit2;                       // defined, never stored
      }
    }
  }
  __syncthreads();               // all h1 reads done; overlay h2

  {
    const int shift = quad >> 1;
    const int c2b   = (quad & 1) * 4;
    #pragma unroll
    for (int i = 0; i < 5; ++i) {
      const int t = w + 4 * i;
      if (t < nt2) {
        const int jl = 32 * t + 2 * n + shift;
        if (jl < jspan) {
          #pragma unroll
          for (int r = 0; r < 4; ++r)
            h2f[(c2b + r) * 516 + jl] = (f16)fmaxf(Ci[i][r], 0.0f);
        }
      }
    }
    if (tid < 8) {               // zero h2 pads [jspan,516)
      for (int r2 = jspan; r2 < 516; ++r2) h2f[tid * 516 + r2] = (f16)0.0f;
    }
  }
  __syncthreads();

  // ---- stage 3 (MFMA): rows 0-7 = cc @ p, rows 8-15 = cc @ p+1; pool ----
  float pool4[4] = {0.0f, 0.0f, 0.0f, 0.0f};
  {
    const f16x8 af3 = *(const f16x8*)(a3 + ((size_t)d * 64 + lane) * 8);
    const f32x4 cinit3 = *(const f32x4*)(b3 + d * 8 + (quad & 1) * 4);
    const int c2a = quad * 2;
    #pragma unroll
    for (int i = 0; i < 4; ++i) {
      const int t = w + 4 * i;               // 16 tiles, always valid
      const f16* bp = h2f + c2a * 516 + 32 * t + 2 * n;
      union { f16x8 v; f16x2 q[4]; } u;
      u.q[0] = *(const f16x2*)bp;
      u.q[1] = *(const f16x2*)(bp + 2);
      u.q[2] = *(const f16x2*)(bp + 516);
      u.q[3] = *(const f16x2*)(bp + 518);
      const f32x4 C = __builtin_amdgcn_mfma_f32_16x16x32_f16(af3, u.v, cinit3, 0, 0, 0);
      const int pl = 32 * t + 2 * n + (quad >> 1);
      if (pl < ospan) {
        #pragma unroll
        for (int r = 0; r < 4; ++r) pool4[r] += fmaxf(C[r], 0.0f);
      }
    }
  }

  // ---- pool reduction: smem f32[8][128], exact cover, then shuffle ----
  __syncthreads();               // stage-3 h2 reads complete before overwrite
  {
    const int cidx = w * 32 + (quad >> 1) * 16 + n;   // 0..127, unique
    const int ccb  = (quad & 1) * 4;
    #pragma unroll
    for (int r = 0; r < 4; ++r) smem[(ccb + r) * 128 + cidx] = pool4[r];
  }
  __syncthreads();
  {
    const int rc = tid >> 5;     // channel 0..7
    const int rj = tid & 31;
    float s = smem[rc * 128 + rj]      + smem[rc * 128 + rj + 32]
            + smem[rc * 128 + rj + 64] + smem[rc * 128 + rj + 96];
    #pragma unroll
    for (int off = 16; off > 0; off >>= 1) s += __shfl_down(s, off, 32);
    if (rj == 0) pooled[rc] = s;
  }
  __syncthreads();

  // ---- head ----
  if (tid < 10) {
    float acc = (half == 0) ? bh[d * 10 + tid] : 0.0f;   // bias counted once
    #pragma unroll
    for (int c3 = 0; c3 < 8; ++c3)
      acc = fmaf(pooled[c3] * (1.0f / 1021.0f), Wh[d * 80 + tid * 8 + c3], acc);
    part[(((size_t)d * 2 + half) * 512 + b) * 10 + tid] = z[d] * acc;
  }
}

// ---------------- fallback path: exact R7 fp32 kernel ----------------
__global__ __launch_bounds__(256, 6) void ensemble_kernel(
    const int* __restrict__ ids, const float* __restrict__ mask,
    const float* __restrict__ z, const float* __restrict__ tbl,
    const float* __restrict__ W1, const float* __restrict__ b1,
    const float* __restrict__ W2, const float* __restrict__ b2,
    const float* __restrict__ W3, const float* __restrict__ b3,
    const float* __restrict__ Wh, const float* __restrict__ bh,
    float* __restrict__ part)
{
  const int tid  = threadIdx.x;
  const int half = blockIdx.x & 1;
  const int bd   = blockIdx.x >> 1;
  const int b    = bd & 511;
  const int d    = bd >> 9;

  __shared__ float smem[4128];
  __shared__ float red[32];
  __shared__ float pooled[8];

  const int l_lo = half ? 1024 : 0;
  const int l_hi = half ? 2047 : 1029;
  const int j_lo = half ? 512  : 0;
  const int j_hi = half ? 1023 : 514;
  const int o_lo = half ? 512  : 0;
  const int o_hi = half ? 1021 : 512;

  const int*    idrow = ids  + (size_t)b * 4096;
  const float*  mrow  = mask + (size_t)b * 4096;
  const float4* tbl4  = (const float4*)tbl;
  const float*  w1p = W1 + d * 96;
  const float*  w2p = W2 + d * 96;
  const float*  w3p = W3 + d * 192;

  {
    float bia[4];
    #pragma unroll
    for (int c = 0; c < 4; ++c) bia[c] = b1[d * 4 + c];

    #pragma unroll 1
    for (int pass = 0; pass < 2; ++pass) {
      const int l0 = l_lo + 2 * tid + 512 * pass;
      const int p0 = 2 * l0;
      const int4   iv = *(const int4*)(idrow + p0);
      const float4 mv = *(const float4*)(mrow + p0);
      int i4; float m4;
      if (p0 + 4 < 4096) { i4 = idrow[p0 + 4]; m4 = mrow[p0 + 4]; }
      else               { i4 = 0;              m4 = 0.0f; }

      const int   pid[5] = {iv.x, iv.y, iv.z, iv.w, i4};
      const float pm[5]  = {mv.x, mv.y, mv.z, mv.w, m4};

      float a0[4], a1v[4];
      #pragma unroll
      for (int c = 0; c < 4; ++c) { a0[c] = bia[c]; a1v[c] = bia[c]; }

      #pragma unroll
      for (int q = 0; q < 5; ++q) {
        const float4 va = tbl4[(size_t)pid[q] * 2];
        const float4 vb = tbl4[(size_t)pid[q] * 2 + 1];
        const float xe[8] = {va.x * pm[q], va.y * pm[q], va.z * pm[q], va.w * pm[q],
                             vb.x * pm[q], vb.y * pm[q], vb.z * pm[q], vb.w * pm[q]};
        if (q <= 2) {
          #pragma unroll
          for (int c = 0; c < 4; ++c)
            #pragma unroll
            for (int e = 0; e < 8; ++e)
              a0[c] = fmaf(xe[e], w1p[c * 24 + e * 3 + q], a0[c]);
        }
        if (q >= 2) {
          #pragma unroll
          for (int c = 0; c < 4; ++c)
            #pragma unroll
            for (int e = 0; e < 8; ++e)
              a1v[c] = fmaf(xe[e], w1p[c * 24 + e * 3 + (q - 2)], a1v[c]);
        }
      }
      const int rel = l0 - l_lo;
      if (l0 + 1 < l_hi) {
        #pragma unroll
        for (int c = 0; c < 4; ++c)
          *(float2*)(smem + c * 1032 + rel) =
              make_float2(fmaxf(a0[c], 0.0f), fmaxf(a1v[c], 0.0f));
      } else if (l0 < l_hi) {
        #pragma unroll
        for (int c = 0; c < 4; ++c)
          smem[c * 1032 + rel] = fmaxf(a0[c], 0.0f);
      }
    }
    const int lt = l_lo + 1024 + tid;
    if (lt < l_hi) {
      float a0[4];
      #pragma unroll
      for (int c = 0; c < 4; ++c) a0[c] = bia[c];
      #pragma unroll
      for (int k = 0; k < 3; ++k) {
        const int p = 2 * lt + k;
        const int id = idrow[p];
        const float m = mrow[p];
        const float4 va = tbl4[(size_t)id * 2];
        const float4 vb = tbl4[(size_t)id * 2 + 1];
        const float xe[8] = {va.x*m, va.y*m, va.z*m, va.w*m,
                             vb.x*m, vb.y*m, vb.z*m, vb.w*m};
        #pragma unroll
        for (int cc = 0; cc < 4; ++cc)
          #pragma unroll
          for (int e = 0; e < 8; ++e)
            a0[cc] = fmaf(xe[e], w1p[cc * 24 + e * 3 + k], a0[cc]);
      }
      #pragma unroll
      for (int c = 0; c < 4; ++c)
        smem[c * 1032 + 1024 + tid] = fmaxf(a0[c], 0.0f);
    }
  }
  __syncthreads();

  float acc2[8][2], acc2t[8];
  {
    #pragma unroll
    for (int c2 = 0; c2 < 8; ++c2) {
      const float bb = b2[d * 8 + c2];
      acc2[c2][0] = bb; acc2[c2][1] = bb; acc2t[c2] = bb;
    }
    const int rel2  = 4 * tid;
    const bool tail2 = tid < (j_hi - j_lo - 512);
    #pragma unroll 1
    for (int c1 = 0; c1 < 4; ++c1) {
      float sw[8][3];
      #pragma unroll
      for (int c2 = 0; c2 < 8; ++c2)
        #pragma unroll
        for (int kk = 0; kk < 3; ++kk)
          sw[c2][kk] = w2p[c2 * 12 + c1 * 3 + kk];
      const float* hp = smem + c1 * 1032;
      const float4 h01 = *(const float4*)(hp + rel2);
      const float  h4v = hp[rel2 + 4];
      #pragma unroll
      for (int c2 = 0; c2 < 8; ++c2) {
        acc2[c2][0] = fmaf(h01.x, sw[c2][0], fmaf(h01.y, sw[c2][1],
                      fmaf(h01.z, sw[c2][2], acc2[c2][0])));
        acc2[c2][1] = fmaf(h01.z, sw[c2][0], fmaf(h01.w, sw[c2][1],
                      fmaf(h4v,   sw[c2][2], acc2[c2][1])));
      }
      if (tail2) {
        const float t0 = hp[1024 + 2 * tid], t1 = hp[1025 + 2 * tid],
                    t2 = hp[1026 + 2 * tid];
        #pragma unroll
        for (int c2 = 0; c2 < 8; ++c2)
          acc2t[c2] = fmaf(t0, sw[c2][0], fmaf(t1, sw[c2][1],
                      fmaf(t2, sw[c2][2], acc2t[c2])));
      }
    }
    #pragma unroll
    for (int c2 = 0; c2 < 8; ++c2) {
      acc2[c2][0] = fmaxf(acc2[c2][0], 0.0f);
      acc2[c2][1] = fmaxf(acc2[c2][1], 0.0f);
      acc2t[c2]   = fmaxf(acc2t[c2],   0.0f);
    }
    __syncthreads();
    const int j0 = j_lo + 2 * tid;
    const int jr = 2 * tid;
    if (j0 + 1 < j_hi) {
      #pragma unroll
      for (int c2 = 0; c2 < 8; ++c2)
        *(float2*)(smem + c2 * 516 + jr) = make_float2(acc2[c2][0], acc2[c2][1]);
    } else if (j0 < j_hi) {
      #pragma unroll
      for (int c2 = 0; c2 < 8; ++c2)
        smem[c2 * 516 + jr] = acc2[c2][0];
    }
    if (tid < (j_hi - j_lo - 512)) {
      #pragma unroll
      for (int c2 = 0; c2 < 8; ++c2)
        smem[c2 * 516 + 512 + tid] = acc2t[c2];
    }
  }
  __syncthreads();

  float acc3[8][2];
  #pragma unroll
  for (int cc = 0; cc < 8; ++cc) {
    const float bb = b3[d * 8 + cc];
    acc3[cc][0] = bb; acc3[cc][1] = bb;
  }
  {
    const int rel3 = 2 * tid;
    #pragma unroll 1
    for (int c2 = 0; c2 < 8; ++c2) {
      float sw[8][3];
      #pragma unroll
      for (int cc = 0; cc < 8; ++cc)
        #pragma unroll
        for (int kk = 0; kk < 3; ++kk)
          sw[cc][kk] = w3p[cc * 24 + c2 * 3 + kk];
      const float* hp = smem + c2 * 516;
      const float2 ha = *(const float2*)(hp + rel3);
      const float2 hb = *(const float2*)(hp + rel3 + 2);
      #pragma unroll
      for (int cc = 0; cc < 8; ++cc) {
        acc3[cc][0] = fmaf(ha.x, sw[cc][0], fmaf(ha.y, sw[cc][1],
                      fmaf(hb.x, sw[cc][2], acc3[cc][0])));
        acc3[cc][1] = fmaf(ha.y, sw[cc][0], fmaf(hb.x, sw[cc][1],
                      fmaf(hb.y, sw[cc][2], acc3[cc][1])));
      }
    }
  }
  const int i0 = o_lo + 2 * tid;
  float psum[8];
  #pragma unroll
  for (int cc = 0; cc < 8; ++cc) {
    float s = 0.0f;
    if (i0 < o_hi)     s += fmaxf(acc3[cc][0], 0.0f);
    if (i0 + 1 < o_hi) s += fmaxf(acc3[cc][1], 0.0f);
    psum[cc] = s;
  }

  const int lane = tid & 63;
  const int wid  = tid >> 6;
  #pragma unroll
  for (int c = 0; c < 8; ++c) {
    float v = psum[c];
    #pragma unroll
    for (int off = 32; off > 0; off >>= 1) v += __shfl_down(v, off, 64);
    if (lane == 0) red[wid * 8 + c] = v;
  }
  __syncthreads();
  if (tid < 8)
    pooled[tid] = red[tid] + red[8 + tid] + red[16 + tid] + red[24 + tid];
  __syncthreads();

  if (tid < 10) {
    float acc = (half == 0) ? bh[d * 10 + tid] : 0.0f;
    #pragma unroll
    for (int c3 = 0; c3 < 8; ++c3)
      acc = fmaf(pooled[c3] * (1.0f / 1021.0f), Wh[d * 80 + tid * 8 + c3], acc);
    part[(((size_t)d * 2 + half) * 512 + b) * 10 + tid] = z[d] * acc;
  }
}

// Fixed-order reduction over 60 (d,half) partials: bitwise-deterministic.
__global__ __launch_bounds__(256) void reduce_kernel(
    const float* __restrict__ part,   // [60][512][10]
    float* __restrict__ out)          // [512][10]
{
  const int i = blockIdx.x * 256 + threadIdx.x;   // 0..5119
  float s = 0.0f;
  #pragma unroll
  for (int dd = 0; dd < 60; ++dd) s += part[dd * 5120 + i];
  out[i] = s;
}

extern "C" void kernel_launch(void* const* d_in, const int* in_sizes, int n_in,
                              void* d_out, int out_size, void* d_ws, size_t ws_size,
                              hipStream_t stream) {
  const int*   ids  = (const int*)d_in[0];
  const float* mask = (const float*)d_in[1];
  const float* z    = (const float*)d_in[2];
  const float* tbl  = (const float*)d_in[3];
  const float* W1   = (const float*)d_in[4];
  const float* b1   = (const float*)d_in[5];
  const float* W2   = (const float*)d_in[6];
  const float* b2   = (const float*)d_in[7];
  const float* W3   = (const float*)d_in[8];
  const float* b3   = (const float*)d_in[9];
  const float* Wh   = (const float*)d_in[10];
  const float* bh   = (const float*)d_in[11];
  float* out  = (float*)d_out;
  float* part = (float*)d_ws;

  const size_t part_bytes = 1228800;                       // [60][512][10] f32
  const size_t a_bytes    = 30720;                         // [30][64][8] f16
  const size_t x_bytes    = (size_t)512 * 8 * 4096 * 2;    // 32 MiB f16
  const size_t need = part_bytes + 3 * a_bytes + x_bytes;

  if (ws_size >= need) {
    f16* a1 = (f16*)((char*)d_ws + part_bytes);
    f16* a2 = (f16*)((char*)d_ws + part_bytes + a_bytes);
    f16* a3 = (f16*)((char*)d_ws + part_bytes + 2 * a_bytes);
    f16* xh = (f16*)((char*)d_ws + part_bytes + 3 * a_bytes);
    hipLaunchKernelGGL(prep_kernel, dim3(4096 + 23), dim3(256), 0, stream,
                       ids, mask, tbl, W1, W2, W3, xh, a1, a2, a3);
    hipLaunchKernelGGL(ensemble_f16_kernel, dim3(512 * 60), dim3(256), 0, stream,
                       xh, a1, a2, a3, z, b1, b2, b3, Wh, bh, part);
  } else {
    hipLaunchKernelGGL(ensemble_kernel, dim3(512 * 30 * 2), dim3(256), 0, stream,
                       ids, mask, z, tbl, W1, b1, W2, b2, W3, b3, Wh, bh, part);
  }
  hipLaunchKernelGGL(reduce_kernel, dim3(20), dim3(256), 0, stream, part, out);
}

// Round 15
// 243.399 us; speedup vs baseline: 1.1142x; 1.1142x over previous
//
#include <hip/hip_runtime.h>
#include <stdint.h>

// FixedConv1DPriorEnsemble: DZ=30 ensemble of conv nets over embedded tokens.
// V=32000 E=8 DZ=30 C=10, CH=(4,8,8), K=3, S=(2,2,1), B=512, L=4096.
//
// History: R8 387 (precompute x); R11 318.7 (f16 dot2); R13 256.3 BEST
//   (dot2 stage 1 + MFMA stages 2/3, half-split blocks, ens 172us);
//   R14 271 REGRESSED (stage-1 MFMA needed 68 scattered 4B loads/thread ->
//   load-bound; revert stage 1 to dot2).
// R15: merge the two half-blocks: f16 LDS makes the full sequence fit in
//   16.5KB (h1 f16[4][2056]; h2 f16[8][1028] overlay) at 8 blocks/CU.
//   Grid 30720->15360: halo/tail code deleted, tile counts exact (32/32),
//   per-block epilogue + A-frag loads amortized 2x, partials 60->30.
//   Stage math identical to verified R13 modulo strides.

typedef _Float16 f16;
typedef f16 f16x2 __attribute__((ext_vector_type(2)));
typedef f16 f16x4 __attribute__((ext_vector_type(4)));
typedef f16 f16x8 __attribute__((ext_vector_type(8)));
typedef float f32x4 __attribute__((ext_vector_type(4)));

static __device__ __forceinline__ float dot2(f16x2 a, f16x2 b, float c) {
#if __has_builtin(__builtin_amdgcn_fdot2)
  return __builtin_amdgcn_fdot2(a, b, c, false);
#else
  return fmaf((float)a.x, (float)b.x, fmaf((float)a.y, (float)b.y, c));
#endif
}
static __device__ __forceinline__ f16x2 ldh(uint32_t u) {
  union { uint32_t u; f16x2 h; } v; v.u = u; return v.h;
}
static __device__ __forceinline__ uint32_t bch(f16x2 h) {
  union { uint32_t u; f16x2 h; } v; v.h = h; return v.u;
}
static __device__ __forceinline__ uint32_t packh(float a, float b) {
  f16x2 p; p.x = (f16)a; p.y = (f16)b; return bch(p);
}

// ---- prep: embed x_f16 + stage-1 dot2 weights + stage-2/3 MFMA A-frags ----
// wp (dwords): d*64 + (e*4+c)*2 -> {w01, w20}
// a2[d][lane][8]: c1=quad, j tap:
//   m<8: j<3 ? W2[m][c1][j] : 0 ; m>=8: 2<=j<5 ? W2[m-8][c1][j-2] : 0
// a3[d][lane][8]: k=quad*8+j -> c2=quad*2+(j>>2), t=j&3:
//   m<8: t<3 ? W3[m][c2][t] : 0 ; m>=8: t>=1 ? W3[m-8][c2][t-1] : 0
__global__ __launch_bounds__(256) void prep_kernel(
    const int* __restrict__ ids, const float* __restrict__ mask,
    const float* __restrict__ tbl,
    const float* __restrict__ W1, const float* __restrict__ W2,
    const float* __restrict__ W3,
    f16* __restrict__ x, uint32_t* __restrict__ wp,
    f16* __restrict__ a2, f16* __restrict__ a3) {
  const int blk = blockIdx.x;
  if (blk < 4096) {                            // embed: 2 tokens/thread
    const int b  = blk >> 3;
    const int l0 = ((blk & 7) * 256 + threadIdx.x) * 2;
    const int2   iv = *(const int2*)(ids + (size_t)b * 4096 + l0);
    const float2 mv = *(const float2*)(mask + (size_t)b * 4096 + l0);
    const float4* t4 = (const float4*)tbl;
    const float4 a0 = t4[(size_t)iv.x * 2], A1 = t4[(size_t)iv.x * 2 + 1];
    const float4 c0 = t4[(size_t)iv.y * 2], C1 = t4[(size_t)iv.y * 2 + 1];
    const float r0[8] = {a0.x, a0.y, a0.z, a0.w, A1.x, A1.y, A1.z, A1.w};
    const float r1[8] = {c0.x, c0.y, c0.z, c0.w, C1.x, C1.y, C1.z, C1.w};
    f16* xb = x + (size_t)b * 8 * 4096 + l0;
    #pragma unroll
    for (int e = 0; e < 8; ++e) {
      f16x2 p; p.x = (f16)(r0[e] * mv.x); p.y = (f16)(r1[e] * mv.y);
      *(f16x2*)(xb + e * 4096) = p;
    }
  } else {
    const int i = (blk - 4096) * 256 + threadIdx.x;
    if (i < 960) {                             // wp: 30*32
      const int d = i / 32, r = i % 32, e = r / 4, c = r % 4;
      const float* w = W1 + d * 96 + c * 24 + e * 3;
      wp[d * 64 + r * 2 + 0] = packh(w[0], w[1]);
      wp[d * 64 + r * 2 + 1] = packh(w[2], 0.0f);
    } else if (i < 2880) {                     // a2: 30*64
      const int idx = i - 960, d = idx >> 6, lane = idx & 63;
      const int quad = lane >> 4, m = lane & 15;
      f16x8 v;
      #pragma unroll
      for (int j = 0; j < 8; ++j) {
        float val = 0.0f;
        if (m < 8)  { if (j < 3)           val = W2[d * 96 + m * 12 + quad * 3 + j]; }
        else        { if (j >= 2 && j < 5) val = W2[d * 96 + (m - 8) * 12 + quad * 3 + (j - 2)]; }
        v[j] = (f16)val;
      }
      *(f16x8*)(a2 + ((size_t)d * 64 + lane) * 8) = v;
    } else if (i < 4800) {                     // a3: 30*64
      const int idx = i - 2880, d = idx >> 6, lane = idx & 63;
      const int quad = lane >> 4, m = lane & 15;
      f16x8 v;
      #pragma unroll
      for (int j = 0; j < 8; ++j) {
        const int c2 = quad * 2 + (j >> 2), t = j & 3;
        float val = 0.0f;
        if (m < 8)  { if (t < 3)  val = W3[d * 192 + m * 24 + c2 * 3 + t]; }
        else        { if (t >= 1) val = W3[d * 192 + (m - 8) * 24 + c2 * 3 + (t - 1)]; }
        v[j] = (f16)val;
      }
      *(f16x8*)(a3 + ((size_t)d * 64 + lane) * 8) = v;
    }
  }
}

// ---------------- fast path: one block per (b,d), full sequence ----------------
__global__ __launch_bounds__(256, 8) void ensemble_f16_kernel(
    const f16* __restrict__ x,        // [512][8][4096]
    const uint32_t* __restrict__ wp,  // stage-1 packed weights
    const f16* __restrict__ a2,       // stage-2 A-fragments [30][64][8]
    const f16* __restrict__ a3,       // stage-3 A-fragments [30][64][8]
    const float* __restrict__ z,
    const float* __restrict__ b1, const float* __restrict__ b2,
    const float* __restrict__ b3,
    const float* __restrict__ Wh, const float* __restrict__ bh,
    float* __restrict__ part)         // [30][512][10]
{
  const int tid = threadIdx.x;
  const int b   = blockIdx.x / 30;    // same-b blocks consecutive (x L2 reuse)
  const int d   = blockIdx.x - b * 30;

  // h1 f16[4][2056] (16448B); h2 f16[8][1028] overlay; pool f32[8][128] overlay
  __shared__ float smem[4112];
  __shared__ float pooled[8];
  f16* h1f = (f16*)smem;
  f16* h2f = (f16*)smem;

  const f16*      xb  = x + (size_t)b * 8 * 4096;
  const uint32_t* wq1 = wp + d * 64;

  const int w = tid >> 6, lane = tid & 63, quad = lane >> 4, n = lane & 15;

  // zero h1 pads [2047,2056) x 4 rows (stage-2 tiles over-read up to 2051)
  if (tid < 36) h1f[(tid / 9) * 2056 + 2047 + (tid % 9)] = (f16)0.0f;
  __syncthreads();

  // ---- stage 1: conv1 (E=8 -> 4ch, K=3, stride 2), dot2, 8 outputs/thread ----
  {
    float bia[4];
    #pragma unroll
    for (int c = 0; c < 4; ++c) bia[c] = b1[d * 4 + c];

    #pragma unroll
    for (int g = 0; g < 2; ++g) {
      const int l0 = 8 * tid + 4 * g;         // outputs l0..l0+3 (covers 0..2047)
      const int p0 = 2 * l0;                  // 16B-aligned byte offset
      const bool edge = (p0 + 8 >= 4096);     // only tid==255, g==1

      float A[4][4];
      #pragma unroll
      for (int c = 0; c < 4; ++c)
        #pragma unroll
        for (int o = 0; o < 4; ++o) A[c][o] = bia[c];

      #pragma unroll
      for (int e = 0; e < 8; ++e) {           // fully unrolled (R3 lesson)
        const f16* xe = xb + e * 4096 + p0;
        const f16x4 va = *(const f16x4*)xe;         // P0 P1
        const f16x4 vb = *(const f16x4*)(xe + 4);   // P2 P3
        f16x2 P4;
        if (edge) { P4.x = (f16)0.0f; P4.y = (f16)0.0f; }
        else      { P4 = *(const f16x2*)(xe + 8); }
        const f16x2 P0 = va.lo, P1 = va.hi, P2 = vb.lo, P3 = vb.hi;
        #pragma unroll
        for (int c = 0; c < 4; ++c) {
          const f16x2 w01 = ldh(wq1[(e * 4 + c) * 2]);
          const f16x2 w20 = ldh(wq1[(e * 4 + c) * 2 + 1]);
          A[c][0] = dot2(P0, w01, A[c][0]); A[c][0] = dot2(P1, w20, A[c][0]);
          A[c][1] = dot2(P1, w01, A[c][1]); A[c][1] = dot2(P2, w20, A[c][1]);
          A[c][2] = dot2(P2, w01, A[c][2]); A[c][2] = dot2(P3, w20, A[c][2]);
          A[c][3] = dot2(P3, w01, A[c][3]); A[c][3] = dot2(P4, w20, A[c][3]);
        }
      }
      if (l0 + 3 < 2047) {                    // all but tid255 g1
        #pragma unroll
        for (int c = 0; c < 4; ++c) {
          f16x4 p;
          p.x = (f16)fmaxf(A[c][0], 0.0f); p.y = (f16)fmaxf(A[c][1], 0.0f);
          p.z = (f16)fmaxf(A[c][2], 0.0f); p.w = (f16)fmaxf(A[c][3], 0.0f);
          *(f16x4*)(h1f + c * 2056 + l0) = p; // 8B-aligned ds_write_b64
        }
      } else {                                // tid255 g1: outputs 2044..2046
        #pragma unroll
        for (int c = 0; c < 4; ++c)
          #pragma unroll
          for (int o = 0; o < 4; ++o)
            if (l0 + o < 2047)
              h1f[c * 2056 + l0 + o] = (f16)fmaxf(A[c][o], 0.0f);
      }
    }
  }
  __syncthreads();

  // ---- stage 2 (MFMA): rows 0-7 = c2 @ j, rows 8-15 = c2 @ j+1; 32 tiles ----
  f32x4 Ci[8];
  {
    const f16x8 af2 = *(const f16x8*)(a2 + ((size_t)d * 64 + lane) * 8);
    const f32x4 cinit2 = *(const f32x4*)(b2 + d * 8 + (quad & 1) * 4);
    #pragma unroll
    for (int i = 0; i < 8; ++i) {
      const int t = w + 4 * i;                // 0..31, all valid
      const f16* bp = h1f + quad * 2056 + 64 * t + 4 * n;
      union { f16x8 v; f16x2 q[4]; } u;
      u.q[0] = *(const f16x2*)bp;
      u.q[1] = *(const f16x2*)(bp + 2);
      u.q[2] = *(const f16x2*)(bp + 4);
      u.q[3] = *(const f16x2*)(bp + 6);
      Ci[i] = __builtin_amdgcn_mfma_f32_16x16x32_f16(af2, u.v, cinit2, 0, 0, 0);
    }
  }
  __syncthreads();               // all h1 reads done; overlay h2

  {
    const int shift = quad >> 1;
    const int c2b   = (quad & 1) * 4;
    #pragma unroll
    for (int i = 0; i < 8; ++i) {
      const int t  = w + 4 * i;
      const int jl = 32 * t + 2 * n + shift;
      if (jl < 1023) {
        #pragma unroll
        for (int r = 0; r < 4; ++r)
          h2f[(c2b + r) * 1028 + jl] = (f16)fmaxf(Ci[i][r], 0.0f);
      }
    }
    if (tid < 40)                // zero h2 pads [1023,1028) x 8 rows
      h2f[(tid / 5) * 1028 + 1023 + (tid % 5)] = (f16)0.0f;
  }
  __syncthreads();

  // ---- stage 3 (MFMA): rows 0-7 = cc @ p, rows 8-15 = cc @ p+1; pool ----
  float pool4[4] = {0.0f, 0.0f, 0.0f, 0.0f};
  {
    const f16x8 af3 = *(const f16x8*)(a3 + ((size_t)d * 64 + lane) * 8);
    const f32x4 cinit3 = *(const f32x4*)(b3 + d * 8 + (quad & 1) * 4);
    const int c2a = quad * 2;
    #pragma unroll
    for (int i = 0; i < 8; ++i) {
      const int t = w + 4 * i;                // 0..31, all valid
      const f16* bp = h2f + c2a * 1028 + 32 * t + 2 * n;
      union { f16x8 v; f16x2 q[4]; } u;
      u.q[0] = *(const f16x2*)bp;
      u.q[1] = *(const f16x2*)(bp + 2);
      u.q[2] = *(const f16x2*)(bp + 1028);
      u.q[3] = *(const f16x2*)(bp + 1030);
      const f32x4 C = __builtin_amdgcn_mfma_f32_16x16x32_f16(af3, u.v, cinit3, 0, 0, 0);
      const int pl = 32 * t + 2 * n + (quad >> 1);
      if (pl < 1021) {
        #pragma unroll
        for (int r = 0; r < 4; ++r) pool4[r] += fmaxf(C[r], 0.0f);
      }
    }
  }

  // ---- pool reduction: smem f32[8][128], exact cover, then shuffle ----
  __syncthreads();               // stage-3 h2 reads complete before overwrite
  {
    const int cidx = w * 32 + (quad >> 1) * 16 + n;   // 0..127, unique
    const int ccb  = (quad & 1) * 4;
    #pragma unroll
    for (int r = 0; r < 4; ++r) smem[(ccb + r) * 128 + cidx] = pool4[r];
  }
  __syncthreads();
  {
    const int rc = tid >> 5;     // channel 0..7
    const int rj = tid & 31;
    float s = smem[rc * 128 + rj]      + smem[rc * 128 + rj + 32]
            + smem[rc * 128 + rj + 64] + smem[rc * 128 + rj + 96];
    #pragma unroll
    for (int off = 16; off > 0; off >>= 1) s += __shfl_down(s, off, 32);
    if (rj == 0) pooled[rc] = s;
  }
  __syncthreads();

  // ---- head ----
  if (tid < 10) {
    float acc = bh[d * 10 + tid];
    #pragma unroll
    for (int c3 = 0; c3 < 8; ++c3)
      acc = fmaf(pooled[c3] * (1.0f / 1021.0f), Wh[d * 80 + tid * 8 + c3], acc);
    part[((size_t)d * 512 + b) * 10 + tid] = z[d] * acc;
  }
}

// Fixed-order reduction over 30 d-partials: bitwise-deterministic.
__global__ __launch_bounds__(256) void reduce30_kernel(
    const float* __restrict__ part,   // [30][512][10]
    float* __restrict__ out)          // [512][10]
{
  const int i = blockIdx.x * 256 + threadIdx.x;   // 0..5119
  float s = 0.0f;
  #pragma unroll
  for (int dd = 0; dd < 30; ++dd) s += part[dd * 5120 + i];
  out[i] = s;
}

// ---------------- fallback path: exact R7 fp32 kernel (60 partials) ----------------
__global__ __launch_bounds__(256, 6) void ensemble_kernel(
    const int* __restrict__ ids, const float* __restrict__ mask,
    const float* __restrict__ z, const float* __restrict__ tbl,
    const float* __restrict__ W1, const float* __restrict__ b1,
    const float* __restrict__ W2, const float* __restrict__ b2,
    const float* __restrict__ W3, const float* __restrict__ b3,
    const float* __restrict__ Wh, const float* __restrict__ bh,
    float* __restrict__ part)
{
  const int tid  = threadIdx.x;
  const int half = blockIdx.x & 1;
  const int bd   = blockIdx.x >> 1;
  const int b    = bd & 511;
  const int d    = bd >> 9;

  __shared__ float smem[4128];
  __shared__ float red[32];
  __shared__ float pooled[8];

  const int l_lo = half ? 1024 : 0;
  const int l_hi = half ? 2047 : 1029;
  const int j_lo = half ? 512  : 0;
  const int j_hi = half ? 1023 : 514;
  const int o_lo = half ? 512  : 0;
  const int o_hi = half ? 1021 : 512;

  const int*    idrow = ids  + (size_t)b * 4096;
  const float*  mrow  = mask + (size_t)b * 4096;
  const float4* tbl4  = (const float4*)tbl;
  const float*  w1p = W1 + d * 96;
  const float*  w2p = W2 + d * 96;
  const float*  w3p = W3 + d * 192;

  {
    float bia[4];
    #pragma unroll
    for (int c = 0; c < 4; ++c) bia[c] = b1[d * 4 + c];

    #pragma unroll 1
    for (int pass = 0; pass < 2; ++pass) {
      const int l0 = l_lo + 2 * tid + 512 * pass;
      const int p0 = 2 * l0;
      const int4   iv = *(const int4*)(idrow + p0);
      const float4 mv = *(const float4*)(mrow + p0);
      int i4; float m4;
      if (p0 + 4 < 4096) { i4 = idrow[p0 + 4]; m4 = mrow[p0 + 4]; }
      else               { i4 = 0;              m4 = 0.0f; }

      const int   pid[5] = {iv.x, iv.y, iv.z, iv.w, i4};
      const float pm[5]  = {mv.x, mv.y, mv.z, mv.w, m4};

      float a0[4], a1v[4];
      #pragma unroll
      for (int c = 0; c < 4; ++c) { a0[c] = bia[c]; a1v[c] = bia[c]; }

      #pragma unroll
      for (int q = 0; q < 5; ++q) {
        const float4 va = tbl4[(size_t)pid[q] * 2];
        const float4 vb = tbl4[(size_t)pid[q] * 2 + 1];
        const float xe[8] = {va.x * pm[q], va.y * pm[q], va.z * pm[q], va.w * pm[q],
                             vb.x * pm[q], vb.y * pm[q], vb.z * pm[q], vb.w * pm[q]};
        if (q <= 2) {
          #pragma unroll
          for (int c = 0; c < 4; ++c)
            #pragma unroll
            for (int e = 0; e < 8; ++e)
              a0[c] = fmaf(xe[e], w1p[c * 24 + e * 3 + q], a0[c]);
        }
        if (q >= 2) {
          #pragma unroll
          for (int c = 0; c < 4; ++c)
            #pragma unroll
            for (int e = 0; e < 8; ++e)
              a1v[c] = fmaf(xe[e], w1p[c * 24 + e * 3 + (q - 2)], a1v[c]);
        }
      }
      const int rel = l0 - l_lo;
      if (l0 + 1 < l_hi) {
        #pragma unroll
        for (int c = 0; c < 4; ++c)
          *(float2*)(smem + c * 1032 + rel) =
              make_float2(fmaxf(a0[c], 0.0f), fmaxf(a1v[c], 0.0f));
      } else if (l0 < l_hi) {
        #pragma unroll
        for (int c = 0; c < 4; ++c)
          smem[c * 1032 + rel] = fmaxf(a0[c], 0.0f);
      }
    }
    const int lt = l_lo + 1024 + tid;
    if (lt < l_hi) {
      float a0[4];
      #pragma unroll
      for (int c = 0; c < 4; ++c) a0[c] = bia[c];
      #pragma unroll
      for (int k = 0; k < 3; ++k) {
        const int p = 2 * lt + k;
        const int id = idrow[p];
        const float m = mrow[p];
        const float4 va = tbl4[(size_t)id * 2];
        const float4 vb = tbl4[(size_t)id * 2 + 1];
        const float xe[8] = {va.x*m, va.y*m, va.z*m, va.w*m,
                             vb.x*m, vb.y*m, vb.z*m, vb.w*m};
        #pragma unroll
        for (int cc = 0; cc < 4; ++cc)
          #pragma unroll
          for (int e = 0; e < 8; ++e)
            a0[cc] = fmaf(xe[e], w1p[cc * 24 + e * 3 + k], a0[cc]);
      }
      #pragma unroll
      for (int c = 0; c < 4; ++c)
        smem[c * 1032 + 1024 + tid] = fmaxf(a0[c], 0.0f);
    }
  }
  __syncthreads();

  float acc2[8][2], acc2t[8];
  {
    #pragma unroll
    for (int c2 = 0; c2 < 8; ++c2) {
      const float bb = b2[d * 8 + c2];
      acc2[c2][0] = bb; acc2[c2][1] = bb; acc2t[c2] = bb;
    }
    const int rel2  = 4 * tid;
    const bool tail2 = tid < (j_hi - j_lo - 512);
    #pragma unroll 1
    for (int c1 = 0; c1 < 4; ++c1) {
      float sw[8][3];
      #pragma unroll
      for (int c2 = 0; c2 < 8; ++c2)
        #pragma unroll
        for (int kk = 0; kk < 3; ++kk)
          sw[c2][kk] = w2p[c2 * 12 + c1 * 3 + kk];
      const float* hp = smem + c1 * 1032;
      const float4 h01 = *(const float4*)(hp + rel2);
      const float  h4v = hp[rel2 + 4];
      #pragma unroll
      for (int c2 = 0; c2 < 8; ++c2) {
        acc2[c2][0] = fmaf(h01.x, sw[c2][0], fmaf(h01.y, sw[c2][1],
                      fmaf(h01.z, sw[c2][2], acc2[c2][0])));
        acc2[c2][1] = fmaf(h01.z, sw[c2][0], fmaf(h01.w, sw[c2][1],
                      fmaf(h4v,   sw[c2][2], acc2[c2][1])));
      }
      if (tail2) {
        const float t0 = hp[1024 + 2 * tid], t1 = hp[1025 + 2 * tid],
                    t2 = hp[1026 + 2 * tid];
        #pragma unroll
        for (int c2 = 0; c2 < 8; ++c2)
          acc2t[c2] = fmaf(t0, sw[c2][0], fmaf(t1, sw[c2][1],
                      fmaf(t2, sw[c2][2], acc2t[c2])));
      }
    }
    #pragma unroll
    for (int c2 = 0; c2 < 8; ++c2) {
      acc2[c2][0] = fmaxf(acc2[c2][0], 0.0f);
      acc2[c2][1] = fmaxf(acc2[c2][1], 0.0f);
      acc2t[c2]   = fmaxf(acc2t[c2],   0.0f);
    }
    __syncthreads();
    const int j0 = j_lo + 2 * tid;
    const int jr = 2 * tid;
    if (j0 + 1 < j_hi) {
      #pragma unroll
      for (int c2 = 0; c2 < 8; ++c2)
        *(float2*)(smem + c2 * 516 + jr) = make_float2(acc2[c2][0], acc2[c2][1]);
    } else if (j0 < j_hi) {
      #pragma unroll
      for (int c2 = 0; c2 < 8; ++c2)
        smem[c2 * 516 + jr] = acc2[c2][0];
    }
    if (tid < (j_hi - j_lo - 512)) {
      #pragma unroll
      for (int c2 = 0; c2 < 8; ++c2)
        smem[c2 * 516 + 512 + tid] = acc2t[c2];
    }
  }
  __syncthreads();

  float acc3[8][2];
  #pragma unroll
  for (int cc = 0; cc < 8; ++cc) {
    const float bb = b3[d * 8 + cc];
    acc3[cc][0] = bb; acc3[cc][1] = bb;
  }
  {
    const int rel3 = 2 * tid;
    #pragma unroll 1
    for (int c2 = 0; c2 < 8; ++c2) {
      float sw[8][3];
      #pragma unroll
      for (int cc = 0; cc < 8; ++cc)
        #pragma unroll
        for (int kk = 0; kk < 3; ++kk)
          sw[cc][kk] = w3p[cc * 24 + c2 * 3 + kk];
      const float* hp = smem + c2 * 516;
      const float2 ha = *(const float2*)(hp + rel3);
      const float2 hb = *(const float2*)(hp + rel3 + 2);
      #pragma unroll
      for (int cc = 0; cc < 8; ++cc) {
        acc3[cc][0] = fmaf(ha.x, sw[cc][0], fmaf(ha.y, sw[cc][1],
                      fmaf(hb.x, sw[cc][2], acc3[cc][0])));
        acc3[cc][1] = fmaf(ha.y, sw[cc][0], fmaf(hb.x, sw[cc][1],
                      fmaf(hb.y, sw[cc][2], acc3[cc][1])));
      }
    }
  }
  const int i0 = o_lo + 2 * tid;
  float psum[8];
  #pragma unroll
  for (int cc = 0; cc < 8; ++cc) {
    float s = 0.0f;
    if (i0 < o_hi)     s += fmaxf(acc3[cc][0], 0.0f);
    if (i0 + 1 < o_hi) s += fmaxf(acc3[cc][1], 0.0f);
    psum[cc] = s;
  }

  const int lane = tid & 63;
  const int wid  = tid >> 6;
  #pragma unroll
  for (int c = 0; c < 8; ++c) {
    float v = psum[c];
    #pragma unroll
    for (int off = 32; off > 0; off >>= 1) v += __shfl_down(v, off, 64);
    if (lane == 0) red[wid * 8 + c] = v;
  }
  __syncthreads();
  if (tid < 8)
    pooled[tid] = red[tid] + red[8 + tid] + red[16 + tid] + red[24 + tid];
  __syncthreads();

  if (tid < 10) {
    float acc = (half == 0) ? bh[d * 10 + tid] : 0.0f;
    #pragma unroll
    for (int c3 = 0; c3 < 8; ++c3)
      acc = fmaf(pooled[c3] * (1.0f / 1021.0f), Wh[d * 80 + tid * 8 + c3], acc);
    part[(((size_t)d * 2 + half) * 512 + b) * 10 + tid] = z[d] * acc;
  }
}

__global__ __launch_bounds__(256) void reduce60_kernel(
    const float* __restrict__ part,   // [60][512][10]
    float* __restrict__ out)          // [512][10]
{
  const int i = blockIdx.x * 256 + threadIdx.x;
  float s = 0.0f;
  #pragma unroll
  for (int dd = 0; dd < 60; ++dd) s += part[dd * 5120 + i];
  out[i] = s;
}

extern "C" void kernel_launch(void* const* d_in, const int* in_sizes, int n_in,
                              void* d_out, int out_size, void* d_ws, size_t ws_size,
                              hipStream_t stream) {
  const int*   ids  = (const int*)d_in[0];
  const float* mask = (const float*)d_in[1];
  const float* z    = (const float*)d_in[2];
  const float* tbl  = (const float*)d_in[3];
  const float* W1   = (const float*)d_in[4];
  const float* b1   = (const float*)d_in[5];
  const float* W2   = (const float*)d_in[6];
  const float* b2   = (const float*)d_in[7];
  const float* W3   = (const float*)d_in[8];
  const float* b3   = (const float*)d_in[9];
  const float* Wh   = (const float*)d_in[10];
  const float* bh   = (const float*)d_in[11];
  float* out  = (float*)d_out;
  float* part = (float*)d_ws;

  const size_t part_bytes = 1228800;                       // max(30,60)-layout
  const size_t wp_bytes   = 7680;                          // 1920 dwords
  const size_t a_bytes    = 30720;                         // [30][64][8] f16
  const size_t x_bytes    = (size_t)512 * 8 * 4096 * 2;    // 32 MiB f16
  const size_t need = part_bytes + wp_bytes + 2 * a_bytes + x_bytes;

  if (ws_size >= need) {
    uint32_t* wp = (uint32_t*)((char*)d_ws + part_bytes);
    f16*      a2 = (f16*)((char*)d_ws + part_bytes + wp_bytes);
    f16*      a3 = (f16*)((char*)d_ws + part_bytes + wp_bytes + a_bytes);
    f16*      xh = (f16*)((char*)d_ws + part_bytes + wp_bytes + 2 * a_bytes);
    hipLaunchKernelGGL(prep_kernel, dim3(4096 + 19), dim3(256), 0, stream,
                       ids, mask, tbl, W1, W2, W3, xh, wp, a2, a3);
    hipLaunchKernelGGL(ensemble_f16_kernel, dim3(512 * 30), dim3(256), 0, stream,
                       xh, wp, a2, a3, z, b1, b2, b3, Wh, bh, part);
    hipLaunchKernelGGL(reduce30_kernel, dim3(20), dim3(256), 0, stream, part, out);
  } else {
    hipLaunchKernelGGL(ensemble_kernel, dim3(512 * 30 * 2), dim3(256), 0, stream,
                       ids, mask, z, tbl, W1, b1, W2, b2, W3, b3, Wh, bh, part);
    hipLaunchKernelGGL(reduce60_kernel, dim3(20), dim3(256), 0, stream, part, out);
  }
}